// Round 6
// baseline (187.729 us; speedup 1.0000x reference)
//
#include <hip/hip_runtime.h>
#include <hip/hip_bf16.h>
#include <cstdint>

// ---------------- problem constants (fixed by harness) ----------------
constexpr int CBATCH = 32;    // B
constexpr int CT = 800;       // T frames
constexpr int CD = 512;       // eprojs (K)
constexpr int CV = 1024;      // odim (N)
constexpr int CL = 100;       // max label len
constexpr int CM = CBATCH * CT;   // 25600 GEMM rows
constexpr int CS = 2 * CL + 1;    // 201 extended states
constexpr int CSPL = 256;         // padded row: 256 floats = 1024B = ONE global_load_lds per row
constexpr float NEGV = -1e30f;
constexpr float INV_LN2 = 1.4426950408889634f;
constexpr float LN2F = 0.6931471805599453f;

typedef __bf16 bf16x8 __attribute__((ext_vector_type(8)));
typedef float f32x4 __attribute__((ext_vector_type(4)));
typedef unsigned short ushort8 __attribute__((ext_vector_type(8)));

// ---------------- helpers ----------------
__device__ inline unsigned short f2bf(float f) {
  union { float f; unsigned u; } v; v.f = f;
  unsigned u = v.u;
  unsigned r = (u + 0x7fffu + ((u >> 16) & 1u)) >> 16;
  return (unsigned short)r;
}
__device__ inline float bf2f(unsigned short u) {
  unsigned x = (unsigned)u << 16;
  return __builtin_bit_cast(float, x);
}

__device__ inline float fexp2(float x) { return __builtin_amdgcn_exp2f(x); }
__device__ inline float flog2(float x) { return __builtin_amdgcn_logf(x); }

// log2-domain logaddexp: log2(2^x + 2^y)
__device__ inline float lae2_2(float x, float y) {
  float m = fmaxf(x, y);
  float d = fminf(x, y) - m;           // <= 0
  return m + flog2(1.0f + fexp2(d));
}
// 3-way: log2(2^x + 2^y + 2^z)
__device__ inline float lae2_3(float x, float y, float z) {
  float m = fmaxf(fmaxf(x, y), z);     // v_max3
  float s = fexp2(x - m) + fexp2(y - m) + fexp2(z - m);
  return m + flog2(s);
}

// wave_shr:1 — lane i gets lane i-1's value; lane 0 gets `fill`. Pure VALU (DPP).
__device__ inline float dpp_shr1(float x, float fill) {
  int xi = __builtin_bit_cast(int, x);
  int fi = __builtin_bit_cast(int, fill);
  int r = __builtin_amdgcn_update_dpp(fi, xi, 0x138, 0xF, 0xF, false);
  return __builtin_bit_cast(float, r);
}

__device__ inline void gload_lds16(const void* g, void* l) {
  __builtin_amdgcn_global_load_lds(
      (const __attribute__((address_space(1))) unsigned int*)g,
      (__attribute__((address_space(3))) unsigned int*)l, 16, 0, 0);
}

// ---------------- 1. fp32 -> bf16 convert ----------------
__global__ void cvt_kernel(const float* __restrict__ in, unsigned short* __restrict__ out, int n4) {
  int i = blockIdx.x * blockDim.x + threadIdx.x;
  if (i < n4) {
    float4 v = reinterpret_cast<const float4*>(in)[i];
    ushort4 o;
    o.x = f2bf(v.x); o.y = f2bf(v.y); o.z = f2bf(v.z); o.w = f2bf(v.w);
    reinterpret_cast<ushort4*>(out)[i] = o;
  }
}

// ---------------- 2. bf16 MFMA GEMM: C[M,V] = A[M,D] * Bt[V,D]^T + bias (bf16 out) ----
constexpr int GBK = 64;    // K-tile

__global__ __launch_bounds__(256, 2) void gemm_kernel(
    const unsigned short* __restrict__ A,   // [CM, CD] bf16 bits
    const unsigned short* __restrict__ Bt,  // [CV, CD] bf16 bits
    const float* __restrict__ bias,         // [CV]
    unsigned short* __restrict__ C)         // [CM, CV] bf16 bits
{
  __shared__ __align__(16) unsigned short As[128 * GBK];  // 16 KB, linear
  __shared__ __align__(16) unsigned short Bs[128 * GBK];
  const int tid = threadIdx.x;
  const int lane = tid & 63;
  const int wave = tid >> 6;          // 4 waves, 2x2 of 64x64
  const int wr = wave >> 1, wc = wave & 1;
  const int bm = blockIdx.x, bn = blockIdx.y;

  f32x4 acc[4][4] = {};

  for (int k0 = 0; k0 < CD; k0 += GBK) {
#pragma unroll
    for (int i = 0; i < 4; ++i) {
      int c = tid + 256 * i;
      int row = c >> 3, col = (c & 7) * 8;
      gload_lds16(&A[(size_t)(bm * 128 + row) * CD + k0 + col], &As[c * 8]);
      gload_lds16(&Bt[(size_t)(bn * 128 + row) * CD + k0 + col], &Bs[c * 8]);
    }
    __syncthreads();
#pragma unroll
    for (int kk = 0; kk < 2; ++kk) {
      bf16x8 af[4], bfr[4];
#pragma unroll
      for (int m = 0; m < 4; ++m)
        af[m] = *reinterpret_cast<const bf16x8*>(
            &As[(wr * 64 + m * 16 + (lane & 15)) * GBK + kk * 32 + (lane >> 4) * 8]);
#pragma unroll
      for (int n = 0; n < 4; ++n)
        bfr[n] = *reinterpret_cast<const bf16x8*>(
            &Bs[(wc * 64 + n * 16 + (lane & 15)) * GBK + kk * 32 + (lane >> 4) * 8]);
#pragma unroll
      for (int m = 0; m < 4; ++m)
#pragma unroll
        for (int n = 0; n < 4; ++n)
          acc[m][n] = __builtin_amdgcn_mfma_f32_16x16x32_bf16(af[m], bfr[n], acc[m][n], 0, 0, 0);
    }
    __syncthreads();
  }

  // epilogue: C layout col=lane&15, row=(lane>>4)*4+reg  [verified m89/m91]
  float bv[4];
#pragma unroll
  for (int n = 0; n < 4; ++n)
    bv[n] = bias[bn * 128 + wc * 64 + n * 16 + (lane & 15)];
#pragma unroll
  for (int m = 0; m < 4; ++m) {
    int rbase = bm * 128 + wr * 64 + m * 16 + (lane >> 4) * 4;
#pragma unroll
    for (int n = 0; n < 4; ++n) {
      int col = bn * 128 + wc * 64 + n * 16 + (lane & 15);
#pragma unroll
      for (int r = 0; r < 4; ++r)
        C[(size_t)(rbase + r) * CV + col] = f2bf(acc[m][n][r] + bv[n]);
    }
  }
}

// ---------------- 3. fused row log-sum-exp + extended-label gather (bf16 logits) ----
__global__ void lse_gather_kernel(const unsigned short* __restrict__ C,
                                  const int* __restrict__ labels,
                                  float* __restrict__ lpg) {
  const int wave = threadIdx.x >> 6, lane = threadIdx.x & 63;
  const int row = blockIdx.x * 4 + wave;   // bt
  const int b = row / CT;
  const unsigned short* p = C + (size_t)row * CV;
  ushort8 v0 = reinterpret_cast<const ushort8*>(p)[lane * 2];
  ushort8 v1 = reinterpret_cast<const ushort8*>(p)[lane * 2 + 1];
  float f[16];
#pragma unroll
  for (int i = 0; i < 8; ++i) { f[i] = bf2f(v0[i]); f[8 + i] = bf2f(v1[i]); }
  float m = f[0];
#pragma unroll
  for (int i = 1; i < 16; ++i) m = fmaxf(m, f[i]);
#pragma unroll
  for (int off = 32; off >= 1; off >>= 1) m = fmaxf(m, __shfl_xor(m, off));
  float s = 0.f;
#pragma unroll
  for (int i = 0; i < 16; ++i) s += __expf(f[i] - m);
#pragma unroll
  for (int off = 32; off >= 1; off >>= 1) s += __shfl_xor(s, off);
  const float l = m + __logf(s);           // natural-log lse, all lanes have it

  if (lane < 51) {                         // 51 lanes cover 204 >= CS states
    const int* lab = labels + b * CL;
    const int s0 = lane * 4;
    float vals[4];
#pragma unroll
    for (int j = 0; j < 4; ++j) {
      int st = s0 + j;
      if (st >= CS) { vals[j] = NEGV; continue; }
      int e = (st & 1) ? lab[st >> 1] : 0;
      vals[j] = (bf2f(p[e]) - l) * INV_LN2;   // log2 domain
    }
    float4 o; o.x = vals[0]; o.y = vals[1]; o.z = vals[2]; o.w = vals[3];
    reinterpret_cast<float4*>(lpg + (size_t)row * CSPL)[lane] = o;
  }
}

// ---------------- 4. CTC alpha recursion (log2 domain): one wave per batch ----------------
// Rounds 3-5 lesson: hipcc refuses to keep a deep VMEM->VGPR ring live (arrays
// AND named asm outputs both end up shuffled through scratch; VGPR=68<ring
// size). So the prefetch ring lives in LDS instead: one global_load_lds per
// 1024B row into a 32-slot ring (allocator can't touch LDS), counted
// s_waitcnt vmcnt(27) fences (never 0; in-order completion => row t+4 landed),
// and a depth-4 LDS->reg prefetch in four NAMED f32x4 buffers whose lgkmcnt
// the compiler tracks precisely.
constexpr int RING = 32;                 // LDS ring rows (32 KB)

__global__ __launch_bounds__(64, 1) void ctc_kernel(
    const float* __restrict__ lpg, const int* __restrict__ labels,
    const int* __restrict__ ilens, const int* __restrict__ llens,
    float* __restrict__ out) {
  __shared__ __align__(16) float ring[RING * CSPL];   // 32 KB
  __shared__ float sal[224];
  const int b = blockIdx.x;
  const int lane = threadIdx.x;
  const int ilen = ilens[b];
  const int ll = llens[b];
  const int* lab = labels + b * CL;
  const int s0 = lane * 4;

  // skip-transition allow flags: only odd states (j=1,3) can be allowed
  bool al1 = false, al3 = false;
  if (lane < 51) {
    int s1 = s0 + 1;
    if (s1 >= 3 && s1 < CS) al1 = (lab[s1 >> 1] != lab[(s1 >> 1) - 1]);
    int s3 = s0 + 3;
    if (s3 < CS) al3 = (lab[s3 >> 1] != lab[(s3 >> 1) - 1]);
  }

  const float* base = lpg + (size_t)b * CT * CSPL;

  // init from t=0 row (log2 domain)
  f32x4 r0 = reinterpret_cast<const f32x4*>(base)[lane];
  float a0, a1, a2, a3;
  a0 = (lane == 0) ? r0[0] : NEGV;
  a1 = (lane == 0 && ll > 0) ? r0[1] : NEGV;
  a2 = NEGV; a3 = NEGV;

  // prologue: stage rows 1..32 into ring slots (row & 31)
#pragma unroll
  for (int r = 1; r <= RING; ++r)
    gload_lds16(base + (size_t)r * CSPL + lane * 4,
                &ring[(r & (RING - 1)) * CSPL + lane * 4]);

  // rows 1..4 -> named reg buffers (depth-4 LDS->reg prefetch)
  asm volatile("s_waitcnt vmcnt(28)" ::: "memory");   // rows 1..4 landed
  __builtin_amdgcn_sched_barrier(0);
  f32x4 lpA = *reinterpret_cast<const f32x4*>(&ring[1 * CSPL + lane * 4]);
  f32x4 lpB = *reinterpret_cast<const f32x4*>(&ring[2 * CSPL + lane * 4]);
  f32x4 lpC = *reinterpret_cast<const f32x4*>(&ring[3 * CSPL + lane * 4]);
  f32x4 lpD = *reinterpret_cast<const f32x4*>(&ring[4 * CSPL + lane * 4]);

  // Step t (= tb+U): fence ensures row t+4 in LDS (outstanding rows t+5..t+31
  // = 27); read row t+4 into this step's buffer; stage row t+32 into the slot
  // that held row t (its ds_read completed at step t-? <= t); then update.
#define CTC_STEP(LP, U)                                                   \
  {                                                                       \
    const int t_ = tb + (U);                                              \
    asm volatile("s_waitcnt vmcnt(27)" ::: "memory");                     \
    __builtin_amdgcn_sched_barrier(0);                                    \
    f32x4 cur_ = LP;                                                      \
    LP = *reinterpret_cast<const f32x4*>(                                 \
        &ring[(((U) + 5) & 31) * CSPL + lane * 4]);                       \
    gload_lds16(base + (size_t)(t_ + 32) * CSPL + lane * 4,               \
                &ring[(((U) + 1) & 31) * CSPL + lane * 4]);               \
    float na3_ = dpp_shr1(a3, NEGV);                                      \
    float c0_ = lae2_2(a0, na3_);                                         \
    float c1_ = lae2_3(a1, a0, al1 ? na3_ : NEGV);                        \
    float c2_ = lae2_2(a2, a1);                                           \
    float c3_ = lae2_3(a3, a2, al3 ? a1 : NEGV);                          \
    if (t_ < ilen) {                                                      \
      a0 = c0_ + cur_[0]; a1 = c1_ + cur_[1];                             \
      a2 = c2_ + cur_[2]; a3 = c3_ + cur_[3];                             \
    }                                                                     \
  }

  // t = 1..800 (25 x 32 steps); t=800 update masked by (t<ilen), ilen<=800.
  // Tail gloads/reads reach row 832 < CT+64 pad (and next batch's region).
  for (int tb = 1; tb <= CT - 31; tb += 32) {
    CTC_STEP(lpA, 0)  CTC_STEP(lpB, 1)  CTC_STEP(lpC, 2)  CTC_STEP(lpD, 3)
    CTC_STEP(lpA, 4)  CTC_STEP(lpB, 5)  CTC_STEP(lpC, 6)  CTC_STEP(lpD, 7)
    CTC_STEP(lpA, 8)  CTC_STEP(lpB, 9)  CTC_STEP(lpC, 10) CTC_STEP(lpD, 11)
    CTC_STEP(lpA, 12) CTC_STEP(lpB, 13) CTC_STEP(lpC, 14) CTC_STEP(lpD, 15)
    CTC_STEP(lpA, 16) CTC_STEP(lpB, 17) CTC_STEP(lpC, 18) CTC_STEP(lpD, 19)
    CTC_STEP(lpA, 20) CTC_STEP(lpB, 21) CTC_STEP(lpC, 22) CTC_STEP(lpD, 23)
    CTC_STEP(lpA, 24) CTC_STEP(lpB, 25) CTC_STEP(lpC, 26) CTC_STEP(lpD, 27)
    CTC_STEP(lpA, 28) CTC_STEP(lpB, 29) CTC_STEP(lpC, 30) CTC_STEP(lpD, 31)
  }
#undef CTC_STEP

  if (lane < 51) {
    sal[s0 + 0] = a0; sal[s0 + 1] = a1; sal[s0 + 2] = a2; sal[s0 + 3] = a3;
  }
  __syncthreads();
  if (lane == 0) {
    float last = sal[2 * ll];
    float prev = (ll > 0) ? sal[2 * ll - 1] : NEGV;
    float v = lae2_2(last, prev);                // log2 domain
    atomicAdd(out, -v * (LN2F / CBATCH));        // back to natural log
  }
}

// ---------------- launch ----------------
extern "C" void kernel_launch(void* const* d_in, const int* in_sizes, int n_in,
                              void* d_out, int out_size, void* d_ws, size_t ws_size,
                              hipStream_t stream) {
  const float* hpad = (const float*)d_in[0];
  const float* W    = (const float*)d_in[1];
  const float* bias = (const float*)d_in[2];
  const int* labels = (const int*)d_in[3];
  const int* ilens  = (const int*)d_in[4];
  const int* llens  = (const int*)d_in[5];
  float* out = (float*)d_out;

  char* ws = (char*)d_ws;
  size_t off = 0;
  auto alloc = [&](size_t bytes) -> void* {
    void* p = ws + off;
    off = (off + bytes + 255) & ~(size_t)255;
    return p;
  };
  unsigned short* Abf = (unsigned short*)alloc((size_t)CM * CD * 2);        // 26.2 MB
  unsigned short* Wbf = (unsigned short*)alloc((size_t)CV * CD * 2);        //  1.0 MB
  unsigned short* logits = (unsigned short*)alloc((size_t)CM * CV * 2);     // 52.4 MB bf16
  float* lpg    = (float*)alloc((size_t)(CM + 64) * CSPL * 4);              // 26.3 MB (+64-row pad)

  hipMemsetAsync(d_out, 0, sizeof(float), stream);

  cvt_kernel<<<(CM * CD / 4 + 255) / 256, 256, 0, stream>>>(hpad, Abf, CM * CD / 4);
  cvt_kernel<<<(CV * CD / 4 + 255) / 256, 256, 0, stream>>>(W, Wbf, CV * CD / 4);
  gemm_kernel<<<dim3(CM / 128, CV / 128), 256, 0, stream>>>(Abf, Wbf, bias, logits);
  lse_gather_kernel<<<CM / 4, 256, 0, stream>>>(logits, labels, lpg);
  ctc_kernel<<<CBATCH, 64, 0, stream>>>(lpg, labels, ilens, llens, out);
}